// Round 2
// baseline (367.100 us; speedup 1.0000x reference)
//
#include <hip/hip_runtime.h>
#include <math.h>

// GaussianPMIModel: mean/cov over X_train (50000x32 f32), then for each eval
// point (100000x32) and each of the 496 (i<j) pairs compute
// exp(lp_diag - lp_full) for the 2x2 Gaussian; output (100000, 529) f32 with
// first 33 columns == 1.0.
//
// Closed form per pair: val = exp(A*dxi^2 + B*dxj^2 + C*dxi*dxj + K) with
//   det = vi*vj - c^2, A = 0.5*c^2/(vi*det), B = 0.5*c^2/(vj*det),
//   C = -c/det, K = 0.5*log(det/(vi*vj)).   (log(2pi) terms cancel.)
//
// R2 structure: pmi kernel maps thread->column (coeffs in REGISTERS, loaded
// once per block; cols<33 use A=B=C=K=0 so exp2(0)=1 unifies the ones path),
// loops over 50 rows/block. Stores are lane-consecutive dwords (coalesced),
// nontemporal (output 211MB >> L2). dx staged once per block in LDS.

#define D       32
#define NPAIRS  496
#define NTRAIN  50000
#define NEVAL   100000
#define OUTC    529          // 1 + 32 + 496
#define ROWS_PB 50           // eval rows per block in main kernel (100000/50=2000)
#define COV_CHUNK 128        // train rows per block in cov kernel
#define MEAN_CHUNK 512       // train rows per block in mean kernel

// ws float layout:
//   [0,32)       column sums (atomic)
//   [32,560)     cov sums: diag at 32+i, pair p at 64+p (atomic)
//   [560,1056)   A
//   [1056,1552)  B
//   [1552,2048)  C
//   [2048,2544)  K
//   [2544,3040)  packed (i | j<<8), stored as int
//   [3040,3072)  mean

__global__ void zero_ws_kernel(float* ws) {
    int t = blockIdx.x * blockDim.x + threadIdx.x;
    if (t < 560) ws[t] = 0.0f;
}

__global__ __launch_bounds__(256) void mean_kernel(const float* __restrict__ X,
                                                   float* __restrict__ ws) {
    __shared__ float sdata[256];
    int t = threadIdx.x;
    int col = t & 31;
    int rowoff = t >> 5;                       // 8 rows per sweep, coalesced
    int base = blockIdx.x * MEAN_CHUNK;
    float s = 0.0f;
    for (int r = rowoff; r < MEAN_CHUNK; r += 8) {
        int row = base + r;
        if (row < NTRAIN) s += X[row * D + col];
    }
    sdata[t] = s;
    __syncthreads();
    if (t < 32) {
        float tot = 0.0f;
        #pragma unroll
        for (int w = 0; w < 8; ++w) tot += sdata[t + 32 * w];
        atomicAdd(&ws[t], tot);
    }
}

static __device__ __forceinline__ void emit_cov(float* ws, int i, int j, float v) {
    if (i > j) return;                         // each (i<=j) entry emitted exactly once
    if (i == j) {
        atomicAdd(&ws[32 + i], v);
    } else {
        int p = i * 31 - (i * (i - 1)) / 2 + (j - i - 1);   // combinations order
        atomicAdd(&ws[64 + p], v);
    }
}

__global__ __launch_bounds__(256) void cov_kernel(const float* __restrict__ X,
                                                  float* __restrict__ ws) {
    __shared__ float xs[64 * D];               // 8 KB tile of centered rows
    __shared__ float smean[D];
    int t = threadIdx.x;
    if (t < D) smean[t] = ws[t] * (1.0f / NTRAIN);
    __syncthreads();

    // thread (ti,tj) owns the 2x2 tile rows {2ti,2ti+1} x cols {2tj,2tj+1}
    int ti = t >> 4, tj = t & 15;
    float a00 = 0.f, a01 = 0.f, a10 = 0.f, a11 = 0.f;
    int base = blockIdx.x * COV_CHUNK;
    const float2* xs2 = (const float2*)xs;

    for (int tile = 0; tile < COV_CHUNK; tile += 64) {
        for (int e = t; e < 64 * D; e += 256) {
            int r = e >> 5, c = e & 31;
            int row = base + tile + r;
            xs[e] = (row < NTRAIN) ? (X[row * D + c] - smean[c]) : 0.0f;
        }
        __syncthreads();
        #pragma unroll 4
        for (int r = 0; r < 64; ++r) {
            float2 xi = xs2[r * 16 + ti];      // ds_read_b64, broadcast across 16 lanes
            float2 xj = xs2[r * 16 + tj];      // ds_read_b64, lane-consecutive
            a00 += xi.x * xj.x; a01 += xi.x * xj.y;
            a10 += xi.y * xj.x; a11 += xi.y * xj.y;
        }
        __syncthreads();
    }
    int i0 = 2 * ti, i1 = 2 * ti + 1, j0 = 2 * tj, j1 = 2 * tj + 1;
    emit_cov(ws, i0, j0, a00);
    emit_cov(ws, i0, j1, a01);
    emit_cov(ws, i1, j0, a10);
    emit_cov(ws, i1, j1, a11);
}

__global__ void prep_kernel(float* ws) {
    int t = threadIdx.x;
    if (t < D) ws[3040 + t] = ws[t] * (1.0f / NTRAIN);
    if (t < NPAIRS) {
        // map p -> (i, j), combinations(range(32), 2) order
        int i = 0, rem = t;
        while (rem >= 31 - i) { rem -= 31 - i; ++i; }
        int j = i + 1 + rem;
        const float inv_nm1 = 1.0f / (float)(NTRAIN - 1);
        float vi = ws[32 + i] * inv_nm1;
        float vj = ws[32 + j] * inv_nm1;
        float c  = ws[64 + t] * inv_nm1;
        float det = vi * vj - c * c;
        float invdet = 1.0f / det;
        ws[560  + t] = 0.5f * c * c * invdet / vi;   // A
        ws[1056 + t] = 0.5f * c * c * invdet / vj;   // B
        ws[1552 + t] = -c * invdet;                  // C
        ws[2048 + t] = 0.5f * logf(det / (vi * vj)); // K
        ((int*)ws)[2544 + t] = i | (j << 8);
    }
}

struct Coef { float A, B, C, K; int oi, oj; };

static __device__ __forceinline__ Coef load_coef(const float* __restrict__ ws, int c) {
    const float LOG2E = 1.44269504088896340736f;
    Coef k;
    if (c < 33) {                      // ones-column: exp2(0) == 1.0
        k.A = 0.f; k.B = 0.f; k.C = 0.f; k.K = 0.f; k.oi = 0; k.oj = 0;
    } else {
        int p = c - 33;
        k.A = ws[560  + p] * LOG2E;
        k.B = ws[1056 + p] * LOG2E;
        k.C = ws[1552 + p] * LOG2E;
        k.K = ws[2048 + p] * LOG2E;
        int ij = ((const int*)ws)[2544 + p];
        k.oi = ij & 255; k.oj = ij >> 8;
    }
    return k;
}

static __device__ __forceinline__ float pair_val(const Coef& k,
                                                 const float* __restrict__ dxr) {
    float di = dxr[k.oi];              // broadcast within runs of equal i
    float dj = dxr[k.oj];              // lane-consecutive -> distinct banks
    float e = fmaf(k.A, di * di, fmaf(k.B, dj * dj, fmaf(k.C, di * dj, k.K)));
    return exp2f(e);                   // coeffs pre-scaled by log2(e)
}

__global__ __launch_bounds__(256) void pmi_kernel(const float* __restrict__ x,
                                                  const float* __restrict__ ws,
                                                  float* __restrict__ out) {
    __shared__ float smean[D];
    __shared__ float dx[ROWS_PB * D];
    int t = threadIdx.x;
    if (t < D) smean[t] = ws[3040 + t];

    // Per-thread columns: t, t+256, and t+512 (only t<17). Coeffs in registers.
    Coef c0 = load_coef(ws, t);
    Coef c1 = load_coef(ws, t + 256);
    bool has3 = (t + 512) < OUTC;
    Coef c2 = load_coef(ws, has3 ? t + 512 : 0);
    __syncthreads();                   // smean ready

    int rowbase = blockIdx.x * ROWS_PB;
    const float4* x4 = (const float4*)(x + (size_t)rowbase * D);
    float4* dx4 = (float4*)dx;
    for (int f = t; f < ROWS_PB * D / 4; f += 256) {
        float4 v = x4[f];
        int cb = (f & 7) * 4;          // D/4 == 8 float4 groups per row
        v.x -= smean[cb];     v.y -= smean[cb + 1];
        v.z -= smean[cb + 2]; v.w -= smean[cb + 3];
        dx4[f] = v;
    }
    __syncthreads();

    float* orow = out + (size_t)rowbase * OUTC;
    const float* dxr = dx;
    #pragma unroll 2
    for (int r = 0; r < ROWS_PB; ++r) {
        // lanes write consecutive columns -> coalesced; nt: bypass L2 (streaming)
        __builtin_nontemporal_store(pair_val(c0, dxr), &orow[t]);
        __builtin_nontemporal_store(pair_val(c1, dxr), &orow[t + 256]);
        if (has3)
            __builtin_nontemporal_store(pair_val(c2, dxr), &orow[t + 512]);
        orow += OUTC; dxr += D;
    }
}

extern "C" void kernel_launch(void* const* d_in, const int* in_sizes, int n_in,
                              void* d_out, int out_size, void* d_ws, size_t ws_size,
                              hipStream_t stream) {
    const float* X = (const float*)d_in[0];   // X_train (50000, 32) f32
    const float* x = (const float*)d_in[1];   // x       (100000, 32) f32
    float* out = (float*)d_out;               // (100000, 529) f32
    float* ws  = (float*)d_ws;

    hipLaunchKernelGGL(zero_ws_kernel, dim3(3), dim3(256), 0, stream, ws);
    hipLaunchKernelGGL(mean_kernel, dim3((NTRAIN + MEAN_CHUNK - 1) / MEAN_CHUNK),
                       dim3(256), 0, stream, X, ws);
    hipLaunchKernelGGL(cov_kernel, dim3((NTRAIN + COV_CHUNK - 1) / COV_CHUNK),
                       dim3(256), 0, stream, X, ws);
    hipLaunchKernelGGL(prep_kernel, dim3(1), dim3(512), 0, stream, ws);
    hipLaunchKernelGGL(pmi_kernel, dim3(NEVAL / ROWS_PB), dim3(256), 0, stream,
                       x, ws, out);
}

// Round 3
// 287.140 us; speedup vs baseline: 1.2785x; 1.2785x over previous
//
#include <hip/hip_runtime.h>
#include <math.h>

// GaussianPMIModel: mean/cov over X_train (50000x32 f32), then for each eval
// point (100000x32) and each of the 496 (i<j) pairs compute
// exp(lp_diag - lp_full) for the 2x2 Gaussian; output (100000, 529) f32 with
// first 33 columns == 1.0.
//
// Closed form per pair: val = exp(A*dxi^2 + B*dxj^2 + C*dxi*dxj + K) with
//   det = vi*vj - c^2, A = 0.5*c^2/(vi*det), B = 0.5*c^2/(vj*det),
//   C = -c/det, K = 0.5*log(det/(vi*vj)).   (log(2pi) terms cancel.)
//
// R3: (a) plain stores in pmi_kernel — R2's nontemporal stores on 2116-B
// (non-line-aligned) rows caused partial-line HBM writes (L2 can't merge);
// (b) mean+cov fused into one UNCENTERED moments pass over X_train
// (cov = (Sxx - n*m*m^T)/(n-1)); (c) keep register-coefficient column
// mapping: thread <-> output column, coeffs loaded once, cols<33 unify as
// exp2(0)=1.

#define D       32
#define NPAIRS  496
#define NTRAIN  50000
#define NEVAL   100000
#define OUTC    529          // 1 + 32 + 496
#define ROWS_PB 50           // eval rows per block (100000/50 = 2000 blocks)
#define MOM_CHUNK 128        // train rows per block in moments kernel

// ws float layout:
//   [0,32)       column sums Sx (atomic)
//   [32,560)     Sxx sums: diag at 32+i, pair p at 64+p (atomic)
//   [560,1056)   A      [1056,1552) B      [1552,2048) C      [2048,2544) K
//   [2544,3040)  packed (i | j<<8) as int
//   [3040,3072)  mean

__global__ void zero_ws_kernel(float* ws) {
    int t = blockIdx.x * blockDim.x + threadIdx.x;
    if (t < 560) ws[t] = 0.0f;
}

static __device__ __forceinline__ void emit_sxx(float* ws, int i, int j, float v) {
    if (i > j) return;                         // each (i<=j) entry emitted exactly once
    if (i == j) {
        atomicAdd(&ws[32 + i], v);
    } else {
        int p = i * 31 - (i * (i - 1)) / 2 + (j - i - 1);   // combinations order
        atomicAdd(&ws[64 + p], v);
    }
}

// One pass over X_train: column sums Sx and upper-triangular Sxx (uncentered).
__global__ __launch_bounds__(256) void moments_kernel(const float* __restrict__ X,
                                                      float* __restrict__ ws) {
    __shared__ float xs[64 * D];               // 8 KB tile of raw rows
    __shared__ float sdata[256];
    int t = threadIdx.x;
    int ti = t >> 4, tj = t & 15;              // 2x2 tile: rows {2ti,2ti+1} x cols {2tj,2tj+1}
    float a00 = 0.f, a01 = 0.f, a10 = 0.f, a11 = 0.f;
    float colsum = 0.f;                        // partial sum for col (t & 31)
    int base = blockIdx.x * MOM_CHUNK;
    const float2* xs2 = (const float2*)xs;

    for (int tile = 0; tile < MOM_CHUNK; tile += 64) {
        for (int e = t; e < 64 * D; e += 256) {  // e%32 == t%32: col invariant
            int r = e >> 5;
            int row = base + tile + r;
            float v = (row < NTRAIN) ? X[(size_t)row * D + (e & 31)] : 0.0f;
            xs[e] = v;
            colsum += v;
        }
        __syncthreads();
        #pragma unroll 4
        for (int r = 0; r < 64; ++r) {
            float2 xi = xs2[r * 16 + ti];      // broadcast across 16 lanes
            float2 xj = xs2[r * 16 + tj];      // lane-consecutive
            a00 += xi.x * xj.x; a01 += xi.x * xj.y;
            a10 += xi.y * xj.x; a11 += xi.y * xj.y;
        }
        __syncthreads();
    }
    // reduce column sums: 8 threads share each col c = t & 31
    sdata[t] = colsum;
    __syncthreads();
    if (t < 32) {
        float tot = 0.0f;
        #pragma unroll
        for (int w = 0; w < 8; ++w) tot += sdata[t + 32 * w];
        atomicAdd(&ws[t], tot);
    }
    int i0 = 2 * ti, i1 = 2 * ti + 1, j0 = 2 * tj, j1 = 2 * tj + 1;
    emit_sxx(ws, i0, j0, a00);
    emit_sxx(ws, i0, j1, a01);
    emit_sxx(ws, i1, j0, a10);
    emit_sxx(ws, i1, j1, a11);
}

__global__ void prep_kernel(float* ws) {
    int t = threadIdx.x;
    const float inv_n = 1.0f / (float)NTRAIN;
    const float inv_nm1 = 1.0f / (float)(NTRAIN - 1);
    if (t < D) ws[3040 + t] = ws[t] * inv_n;   // mean
    if (t < NPAIRS) {
        // map p -> (i, j), combinations(range(32), 2) order
        int i = 0, rem = t;
        while (rem >= 31 - i) { rem -= 31 - i; ++i; }
        int j = i + 1 + rem;
        float mi = ws[i] * inv_n, mj = ws[j] * inv_n;
        float vi = (ws[32 + i] - (float)NTRAIN * mi * mi) * inv_nm1;
        float vj = (ws[32 + j] - (float)NTRAIN * mj * mj) * inv_nm1;
        float c  = (ws[64 + t] - (float)NTRAIN * mi * mj) * inv_nm1;
        float det = vi * vj - c * c;
        float invdet = 1.0f / det;
        const float LOG2E = 1.44269504088896340736f;
        ws[560  + t] = 0.5f * c * c * invdet / vi * LOG2E;   // A (pre-scaled)
        ws[1056 + t] = 0.5f * c * c * invdet / vj * LOG2E;   // B
        ws[1552 + t] = -c * invdet * LOG2E;                  // C
        ws[2048 + t] = 0.5f * logf(det / (vi * vj)) * LOG2E; // K
        ((int*)ws)[2544 + t] = i | (j << 8);
    }
}

struct Coef { float A, B, C, K; int oi, oj; };

static __device__ __forceinline__ Coef load_coef(const float* __restrict__ ws, int c) {
    Coef k;
    if (c < 33) {                      // ones-column: exp2(0) == 1.0
        k.A = 0.f; k.B = 0.f; k.C = 0.f; k.K = 0.f; k.oi = 0; k.oj = 0;
    } else {
        int p = c - 33;
        k.A = ws[560  + p];
        k.B = ws[1056 + p];
        k.C = ws[1552 + p];
        k.K = ws[2048 + p];
        int ij = ((const int*)ws)[2544 + p];
        k.oi = ij & 255; k.oj = ij >> 8;
    }
    return k;
}

static __device__ __forceinline__ float pair_val(const Coef& k,
                                                 const float* __restrict__ dxr) {
    float di = dxr[k.oi];              // broadcast within runs of equal i
    float dj = dxr[k.oj];              // mostly lane-consecutive -> distinct banks
    float e = fmaf(k.A, di * di, fmaf(k.B, dj * dj, fmaf(k.C, di * dj, k.K)));
    return exp2f(e);                   // coeffs pre-scaled by log2(e); exp2f -> v_exp_f32
}

__global__ __launch_bounds__(256) void pmi_kernel(const float* __restrict__ x,
                                                  const float* __restrict__ ws,
                                                  float* __restrict__ out) {
    __shared__ float smean[D];
    __shared__ float dx[ROWS_PB * D];
    int t = threadIdx.x;
    if (t < D) smean[t] = ws[3040 + t];

    // Per-thread columns: t, t+256, and t+512 (only t<17). Coeffs in registers.
    Coef c0 = load_coef(ws, t);
    Coef c1 = load_coef(ws, t + 256);
    bool has3 = (t + 512) < OUTC;
    Coef c2 = load_coef(ws, has3 ? t + 512 : 0);
    __syncthreads();                   // smean ready

    int rowbase = blockIdx.x * ROWS_PB;
    const float4* x4 = (const float4*)(x + (size_t)rowbase * D);
    float4* dx4 = (float4*)dx;
    for (int f = t; f < ROWS_PB * D / 4; f += 256) {
        float4 v = x4[f];
        int cb = (f & 7) * 4;          // D/4 == 8 float4 groups per row
        v.x -= smean[cb];     v.y -= smean[cb + 1];
        v.z -= smean[cb + 2]; v.w -= smean[cb + 3];
        dx4[f] = v;
    }
    __syncthreads();

    float* orow = out + (size_t)rowbase * OUTC;
    const float* dxr = dx;
    #pragma unroll 2
    for (int r = 0; r < ROWS_PB; ++r) {
        // lanes write consecutive columns -> coalesced; plain stores so L2
        // merges adjacent waves' 256B spans into full lines (rows are 2116 B,
        // not line-aligned — nt stores caused partial-line HBM writes in R2).
        orow[t]       = pair_val(c0, dxr);
        orow[t + 256] = pair_val(c1, dxr);
        if (has3) orow[t + 512] = pair_val(c2, dxr);
        orow += OUTC; dxr += D;
    }
}

extern "C" void kernel_launch(void* const* d_in, const int* in_sizes, int n_in,
                              void* d_out, int out_size, void* d_ws, size_t ws_size,
                              hipStream_t stream) {
    const float* X = (const float*)d_in[0];   // X_train (50000, 32) f32
    const float* x = (const float*)d_in[1];   // x       (100000, 32) f32
    float* out = (float*)d_out;               // (100000, 529) f32
    float* ws  = (float*)d_ws;

    hipLaunchKernelGGL(zero_ws_kernel, dim3(3), dim3(256), 0, stream, ws);
    hipLaunchKernelGGL(moments_kernel, dim3((NTRAIN + MOM_CHUNK - 1) / MOM_CHUNK),
                       dim3(256), 0, stream, X, ws);
    hipLaunchKernelGGL(prep_kernel, dim3(1), dim3(512), 0, stream, ws);
    hipLaunchKernelGGL(pmi_kernel, dim3(NEVAL / ROWS_PB), dim3(256), 0, stream,
                       x, ws, out);
}